// Round 9
// baseline (9394.871 us; speedup 1.0000x reference)
//
#include <hip/hip_runtime.h>
#include <math.h>

#define H 64
#define SEQ_T 1024
#define BATCH 512
#define NTHR 256            // waves 0-1: recurrence (ks-2); waves 2-3: xg producers
#define NBLK BATCH          // 1 block = 1 batch row; 512 blocks = 2 blocks/CU
#define CHUNK 32
#define NCHUNK (SEQ_T / CHUNK)   // 32
#define LOG2E 1.44269504088896340736f

// Barrier that drains ONLY LDS ops (global loads/stores stay in flight).
#define LDS_BARRIER() asm volatile("s_waitcnt lgkmcnt(0)\n\ts_barrier" ::: "memory")

#define FMA_H(hv, q)                                                            \
    hr = fmaf((hv).x, wHv[0][q].x, hr); hr = fmaf((hv).y, wHv[0][q].y, hr);     \
    hr = fmaf((hv).z, wHv[0][q].z, hr); hr = fmaf((hv).w, wHv[0][q].w, hr);     \
    hz = fmaf((hv).x, wHv[1][q].x, hz); hz = fmaf((hv).y, wHv[1][q].y, hz);     \
    hz = fmaf((hv).z, wHv[1][q].z, hz); hz = fmaf((hv).w, wHv[1][q].w, hz);     \
    hn = fmaf((hv).x, wHv[2][q].x, hn); hn = fmaf((hv).y, wHv[2][q].y, hn);     \
    hn = fmaf((hv).z, wHv[2][q].z, hn); hn = fmaf((hv).w, wHv[2][q].w, hn);

#define BPERM_ADD(v)                                                            \
    v += __int_as_float(__builtin_amdgcn_ds_bpermute(bpaddr, __float_as_int(v)));

// ---- recurrence step (waves 0-1, ks-2). PR: compile-time hbuf parity. ----
// xgrow = &xg[buf][tloc][0] (xg already includes input-side dot + b_ih).
template <int PR>
__device__ __forceinline__ void rec_step(
    const float* __restrict__ xgrow, float (*hbuf)[H],
    const float4 (&wHv)[3][8],
    float bRh, float bZh, float bNh,
    float& hprev, int j, int k0, int ks, int bpaddr,
    float*& pSt, bool dostore)
{
    const float4* hb4 = (const float4*)(&hbuf[PR][k0]);
    float4 h0 = hb4[0], h1 = hb4[1], h2 = hb4[2], h3 = hb4[3];
    float4 h4 = hb4[4], h5 = hb4[5], h6 = hb4[6], h7 = hb4[7];
    float xr_ = xgrow[j];            // full input-side preact (r)
    float xz_ = xgrow[j + 64];       // (z)
    float xn_ = xgrow[j + 128];      // (n), includes b_ih n-part

    float hr = 0.f, hz = 0.f, hn = 0.f;
    FMA_H(h0, 0) FMA_H(h1, 1) FMA_H(h2, 2) FMA_H(h3, 3)
    FMA_H(h4, 4) FMA_H(h5, 5) FMA_H(h6, 6) FMA_H(h7, 7)

    // single-stage reduce across the 2 k-slices (xor 32) — only 3 values now
    BPERM_ADD(hr) BPERM_ADD(hz) BPERM_ADD(hn)

    float r = __builtin_amdgcn_rcpf(
        1.0f + __builtin_amdgcn_exp2f((xr_ + hr + bRh) * -LOG2E));
    float z = __builtin_amdgcn_rcpf(
        1.0f + __builtin_amdgcn_exp2f((xz_ + hz + bZh) * -LOG2E));
    float u_ = xn_ + r * (hn + bNh);
    float e2_ = __builtin_amdgcn_exp2f(fabsf(u_) * (2.0f * LOG2E));
    float t_ = fmaf(-2.0f, __builtin_amdgcn_rcpf(e2_ + 1.0f), 1.0f);
    float n = copysignf(t_, u_);
    float hnew = fmaf(z, hprev - n, n);   // (1-z)*n + z*h
    hprev = hnew;
    if (ks == 0) {
        hbuf[PR ^ 1][j] = hnew;
        if (dostore) *pSt = hnew;
    }
    pSt += H;
}

// ---- producer: one 64-MAC xg dot (mid layers) ----
__device__ __forceinline__ void prod_out_mid(
    float* __restrict__ xgw, const float* __restrict__ actb,
    int cnext, int t, int gj, const float4 (&w)[16], float bias)
{
    const float4* x4 = (const float4*)(actb + ((size_t)cnext * CHUNK + t) * H);
    float a0 = 0.f, a1 = 0.f, a2 = 0.f, a3 = 0.f;
    #pragma unroll
    for (int q = 0; q < 16; q += 4) {
        float4 xv;
        xv = x4[q + 0];
        a0 = fmaf(xv.x, w[q+0].x, a0); a0 = fmaf(xv.y, w[q+0].y, a0);
        a0 = fmaf(xv.z, w[q+0].z, a0); a0 = fmaf(xv.w, w[q+0].w, a0);
        xv = x4[q + 1];
        a1 = fmaf(xv.x, w[q+1].x, a1); a1 = fmaf(xv.y, w[q+1].y, a1);
        a1 = fmaf(xv.z, w[q+1].z, a1); a1 = fmaf(xv.w, w[q+1].w, a1);
        xv = x4[q + 2];
        a2 = fmaf(xv.x, w[q+2].x, a2); a2 = fmaf(xv.y, w[q+2].y, a2);
        a2 = fmaf(xv.z, w[q+2].z, a2); a2 = fmaf(xv.w, w[q+2].w, a2);
        xv = x4[q + 3];
        a3 = fmaf(xv.x, w[q+3].x, a3); a3 = fmaf(xv.y, w[q+3].y, a3);
        a3 = fmaf(xv.z, w[q+3].z, a3); a3 = fmaf(xv.w, w[q+3].w, a3);
    }
    xgw[t * 192 + gj] = bias + ((a0 + a1) + (a2 + a3));
}

// ---- producer: layer-0 dot (K = 5) ----
__device__ __forceinline__ void prod_out_l0(
    float* __restrict__ xgw, const float* __restrict__ xb,
    int cnext, int t, int gj, const float4 (&w)[16], float bias)
{
    const float* xr = xb + ((size_t)cnext * CHUNK + t) * 5;
    float a = fmaf(xr[0], w[0].x, fmaf(xr[1], w[0].y,
              fmaf(xr[2], w[0].z, fmaf(xr[3], w[0].w, xr[4] * w[1].x))));
    xgw[t * 192 + gj] = bias + a;
}

// n outputs starting at flat index o0 (o<32: primary row, all t; o>=32:
// secondary row, split t). All branches are thread-uniform-in-time per o.
__device__ __forceinline__ void prod_n(
    bool l0, int o0, int nout, int cnext, float* __restrict__ xgw,
    const float* __restrict__ actb, const float* __restrict__ xb,
    const float4 (&wp)[16], const float4 (&ws)[16],
    float bp, float bs, int pg, int sg, int tb)
{
    for (int i = 0; i < nout; ++i) {
        int o = o0 + i;
        if (o < 32) {
            if (l0) prod_out_l0(xgw, xb, cnext, o, pg, wp, bp);
            else    prod_out_mid(xgw, actb, cnext, o, pg, wp, bp);
        } else {
            int t = tb + (o - 32);
            if (l0) prod_out_l0(xgw, xb, cnext, t, sg, ws, bs);
            else    prod_out_mid(xgw, actb, cnext, t, sg, ws, bs);
        }
    }
}

__global__ __launch_bounds__(NTHR, 2) void gru_all_kernel(
    const float* __restrict__ x,
    const float* __restrict__ w_ih0, const float* __restrict__ w_hh0,
    const float* __restrict__ b_ih0, const float* __restrict__ b_hh0,
    const float* __restrict__ w_ih, const float* __restrict__ w_hh,
    const float* __restrict__ b_ih, const float* __restrict__ b_hh,
    const float* __restrict__ w_fc, const float* __restrict__ b_fc,
    float* __restrict__ out, float* __restrict__ act)
{
    __shared__ __align__(16) float xg[2][CHUNK][192];   // 48 KiB, double-buffered
    __shared__ __align__(16) float hbuf[2][H];
    __shared__ float partial[2];

    const int tid  = threadIdx.x;
    const int wv   = tid >> 6;
    const int lane = tid & 63;
    const int b    = blockIdx.x;
    // recurrence mapping (waves 0-1): j = 32*wv + jl, k-slice = 32*ks
    const int jl = lane & 31;
    const int ks = lane >> 5;
    const int j  = wv * 32 + jl;
    const int k0 = ks * 32;
    const int bpaddr = (lane ^ 32) << 2;
    // producer mapping (waves 2-3): primary row pg (all 32 t),
    // secondary row sg shared by thread pair (t split 0-15 / 16-31)
    const int m  = tid & 127;
    const int pg = m;
    const int sg = 128 + (m & 63);
    const int tb = (m < 64) ? 0 : 16;

    float* __restrict__ actb = act + (size_t)b * (SEQ_T * H);
    const float* __restrict__ xb = x + (size_t)b * (SEQ_T * 5);

    float hlast = 0.0f;

    for (int layer = 0; layer < 5; ++layer) {
        // Full drain: prev layer's act stores (vmcnt) visible to this
        // layer's producers; LDS quiesced before xg[0] refill.
        __syncthreads();

        const bool l0 = (layer == 0);
        const bool dostore = (layer < 4);

        float4 wHv[3][8];
        float bRh = 0.f, bZh = 0.f, bNh = 0.f;
        float4 wp4[16], ws4[16];
        float bp = 0.f, bs = 0.f;
        float hprev = 0.0f;

        if (wv < 2) {
            // ---- recurrence weights: hidden-side k-slice -> VGPRs ----
            const float* whp = l0 ? w_hh0 : w_hh + (size_t)(layer - 1) * (192 * H);
            #pragma unroll
            for (int g = 0; g < 3; ++g) {
                const float4* row = (const float4*)(whp + (g * 64 + j) * H + k0);
                #pragma unroll
                for (int q = 0; q < 8; ++q) wHv[g][q] = row[q];
            }
            const float* bhp = l0 ? b_hh0 : b_hh + (layer - 1) * 192;
            bRh = bhp[j]; bZh = bhp[j + 64]; bNh = bhp[j + 128];
            if (ks == 0) hbuf[0][j] = 0.0f;   // h0 = 0
        } else {
            // ---- producer weights: input-side rows pg, sg -> VGPRs ----
            const float* bip = l0 ? b_ih0 : b_ih + (layer - 1) * 192;
            bp = bip[pg]; bs = bip[sg];
            if (l0) {
                #pragma unroll
                for (int q = 0; q < 16; ++q) { wp4[q] = make_float4(0,0,0,0); ws4[q] = make_float4(0,0,0,0); }
                const float* r1 = w_ih0 + pg * 5;
                wp4[0] = make_float4(r1[0], r1[1], r1[2], r1[3]); wp4[1].x = r1[4];
                const float* r2 = w_ih0 + sg * 5;
                ws4[0] = make_float4(r2[0], r2[1], r2[2], r2[3]); ws4[1].x = r2[4];
            } else {
                const float* wip = w_ih + (size_t)(layer - 1) * (192 * H);
                const float4* rp = (const float4*)(wip + pg * H);
                const float4* rs = (const float4*)(wip + sg * H);
                #pragma unroll
                for (int q = 0; q < 16; ++q) { wp4[q] = rp[q]; ws4[q] = rs[q]; }
            }
        }

        // ---- prologue: producers fill xg[0] with chunk 0 ----
        if (wv >= 2)
            prod_n(l0, 0, 48, 0, &xg[0][0][0], actb, xb,
                   wp4, ws4, bp, bs, pg, sg, tb);
        __syncthreads();   // xg[0] + hbuf[0] visible

        float* pSt = actb + j;   // recurrence store pointer (waves 0-1)

        for (int c = 0; c < NCHUNK; ++c) {
            const float* xgr = &xg[c & 1][0][0];
            float* xgw = &xg[(c + 1) & 1][0][0];
            const bool hasnext = (c + 1 < NCHUNK);
            for (int tt = 0; tt < CHUNK / 2; ++tt) {
                if (wv < 2)
                    rec_step<0>(xgr + (2 * tt) * 192, hbuf, wHv, bRh, bZh, bNh,
                                hprev, j, k0, ks, bpaddr, pSt, dostore);
                else if (hasnext)
                    prod_n(l0, 3 * tt, 2, c + 1, xgw, actb, xb,
                           wp4, ws4, bp, bs, pg, sg, tb);
                LDS_BARRIER();
                if (wv < 2)
                    rec_step<1>(xgr + (2 * tt + 1) * 192, hbuf, wHv, bRh, bZh, bNh,
                                hprev, j, k0, ks, bpaddr, pSt, dostore);
                else if (hasnext)
                    prod_n(l0, 3 * tt + 2, 1, c + 1, xgw, actb, xb,
                           wp4, ws4, bp, bs, pg, sg, tb);
                LDS_BARRIER();
            }
        }

        if (layer == 4) hlast = hprev;
    }

    // ---- fused FC on last timestep: out[b] = h . w_fc + b_fc ----
    float v = 0.0f;
    if (wv < 2 && ks == 0) v = hlast * w_fc[j];
    v += __shfl_xor(v, 1, 64);
    v += __shfl_xor(v, 2, 64);
    v += __shfl_xor(v, 4, 64);
    v += __shfl_xor(v, 8, 64);
    v += __shfl_xor(v, 16, 64);
    if (wv < 2 && lane == 0) partial[wv] = v;
    __syncthreads();
    if (tid == 0) out[b] = partial[0] + partial[1] + b_fc[0];
}

extern "C" void kernel_launch(void* const* d_in, const int* in_sizes, int n_in,
                              void* d_out, int out_size, void* d_ws, size_t ws_size,
                              hipStream_t stream) {
    const float* x     = (const float*)d_in[0];
    const float* w_ih0 = (const float*)d_in[1];
    const float* w_hh0 = (const float*)d_in[2];
    const float* b_ih0 = (const float*)d_in[3];
    const float* b_hh0 = (const float*)d_in[4];
    const float* w_ih  = (const float*)d_in[5];
    const float* w_hh  = (const float*)d_in[6];
    const float* b_ih  = (const float*)d_in[7];
    const float* b_hh  = (const float*)d_in[8];
    const float* w_fc  = (const float*)d_in[9];
    const float* b_fc  = (const float*)d_in[10];
    float* out = (float*)d_out;
    float* act = (float*)d_ws;  // [BATCH][SEQ_T][H] fp32 = 128 MiB

    hipLaunchKernelGGL(gru_all_kernel, dim3(NBLK), dim3(NTHR), 0, stream,
                       x, w_ih0, w_hh0, b_ih0, b_hh0,
                       w_ih, w_hh, b_ih, b_hh, w_fc, b_fc, out, act);
}

// Round 10
// 3673.326 us; speedup vs baseline: 2.5576x; 2.5576x over previous
//
#include <hip/hip_runtime.h>
#include <math.h>

#define H 64
#define SEQ_T 1024
#define BATCH 512
#define NTHR 256
#define NBLK BATCH          // 1 block = 1 batch row; 512 blocks = 2 blocks/CU
#define CHUNK 32
#define NCHUNK (SEQ_T / CHUNK)   // 32
#define XGS 196             // xg row stride (pad: 196%32=4 -> banks vary with t)
#define LOG2E 1.44269504088896340736f

// Barrier that drains ONLY LDS ops (global loads/stores stay in flight).
#define LDS_BARRIER() asm volatile("s_waitcnt lgkmcnt(0)\n\ts_barrier" ::: "memory")

#define FMA_H(hv, q)                                                            \
    hr = fmaf((hv).x, wHv[0][q].x, hr); hr = fmaf((hv).y, wHv[0][q].y, hr);     \
    hr = fmaf((hv).z, wHv[0][q].z, hr); hr = fmaf((hv).w, wHv[0][q].w, hr);     \
    hz = fmaf((hv).x, wHv[1][q].x, hz); hz = fmaf((hv).y, wHv[1][q].y, hz);     \
    hz = fmaf((hv).z, wHv[1][q].z, hz); hz = fmaf((hv).w, wHv[1][q].w, hz);     \
    hn = fmaf((hv).x, wHv[2][q].x, hn); hn = fmaf((hv).y, wHv[2][q].y, hn);     \
    hn = fmaf((hv).z, wHv[2][q].z, hn); hn = fmaf((hv).w, wHv[2][q].w, hn);

#define XREDUCE(v)                                                              \
    v += __int_as_float(__builtin_amdgcn_ds_swizzle(__float_as_int(v), 0x401F));\
    v += __int_as_float(__builtin_amdgcn_ds_bpermute(bpaddr, __float_as_int(v)));

// ---- one recurrence step: h-side matvec only (xg precomputed in LDS) ----
// PR: compile-time hbuf parity. Round-8 mapping: j = 16wv+jl, k0 = 16ks.
template <int PR>
__device__ __forceinline__ void rec_step(
    const float* __restrict__ xgrow, float (*hbuf)[H],
    const float4 (&wHv)[3][4],
    float bR, float bZ, float bNi, float bNh,
    float& hprev, int j, int k0, int ks, int bpaddr,
    float*& pSt, bool dostore)
{
    const float4* hb4 = (const float4*)(&hbuf[PR][k0]);
    float4 h0 = hb4[0], h1 = hb4[1], h2 = hb4[2], h3 = hb4[3];
    float xr_ = xgrow[j];          // raw input-side dots (no bias)
    float xz_ = xgrow[j + 64];
    float xn_ = xgrow[j + 128];

    float hr = 0.f, hz = 0.f, hn = 0.f;
    FMA_H(h0, 0) FMA_H(h1, 1) FMA_H(h2, 2) FMA_H(h3, 3)

    // 2-stage reduce over 4 k-slices, 3 values (was 4 pre-split)
    XREDUCE(hr) XREDUCE(hz) XREDUCE(hn)

    float r = __builtin_amdgcn_rcpf(
        1.0f + __builtin_amdgcn_exp2f((xr_ + hr + bR) * -LOG2E));
    float z = __builtin_amdgcn_rcpf(
        1.0f + __builtin_amdgcn_exp2f((xz_ + hz + bZ) * -LOG2E));
    float u_ = xn_ + bNi + r * (hn + bNh);
    float e2_ = __builtin_amdgcn_exp2f(fabsf(u_) * (2.0f * LOG2E));
    float t_ = fmaf(-2.0f, __builtin_amdgcn_rcpf(e2_ + 1.0f), 1.0f);
    float n = copysignf(t_, u_);
    float hnew = fmaf(z, hprev - n, n);   // (1-z)*n + z*h
    hprev = hnew;
    if (ks == 0) {
        hbuf[PR ^ 1][j] = hnew;
        if (dostore) *pSt = hnew;
    }
    pSt += H;
}

// ---- GEMM phase (mid layers): xg[t][g] = act[t][:] . W_ih[g][:] ----
// Thread tile: 2 t-rows x 12 g-cols. act -> registers (batched global loads,
// one latency wait per 16-k pass); W from LDS (k-major).
__device__ __forceinline__ void gemm64(
    const float* __restrict__ actb, int c, int ti, int g0,
    const float* __restrict__ Wt, float* __restrict__ xgl)
{
    const float4* r0 = (const float4*)(actb + (size_t)(c * CHUNK + 2 * ti) * H);
    const float4* r1 = (const float4*)(actb + (size_t)(c * CHUNK + 2 * ti + 1) * H);
    float acc0[12], acc1[12];
    #pragma unroll
    for (int i = 0; i < 12; ++i) { acc0[i] = 0.f; acc1[i] = 0.f; }

    #pragma unroll
    for (int pass = 0; pass < 4; ++pass) {
        float4 a0[4], a1[4];
        #pragma unroll
        for (int q = 0; q < 4; ++q) { a0[q] = r0[pass * 4 + q]; a1[q] = r1[pass * 4 + q]; }
        #pragma unroll
        for (int kq = 0; kq < 4; ++kq) {
            #pragma unroll
            for (int e = 0; e < 4; ++e) {
                const int k = pass * 16 + kq * 4 + e;
                const float4* w = (const float4*)(&Wt[k * 192 + g0]);
                float4 w0 = w[0], w1 = w[1], w2 = w[2];
                float v0 = (e == 0) ? a0[kq].x : (e == 1) ? a0[kq].y : (e == 2) ? a0[kq].z : a0[kq].w;
                float v1 = (e == 0) ? a1[kq].x : (e == 1) ? a1[kq].y : (e == 2) ? a1[kq].z : a1[kq].w;
                acc0[0] = fmaf(v0, w0.x, acc0[0]); acc0[1] = fmaf(v0, w0.y, acc0[1]);
                acc0[2] = fmaf(v0, w0.z, acc0[2]); acc0[3] = fmaf(v0, w0.w, acc0[3]);
                acc0[4] = fmaf(v0, w1.x, acc0[4]); acc0[5] = fmaf(v0, w1.y, acc0[5]);
                acc0[6] = fmaf(v0, w1.z, acc0[6]); acc0[7] = fmaf(v0, w1.w, acc0[7]);
                acc0[8] = fmaf(v0, w2.x, acc0[8]); acc0[9] = fmaf(v0, w2.y, acc0[9]);
                acc0[10] = fmaf(v0, w2.z, acc0[10]); acc0[11] = fmaf(v0, w2.w, acc0[11]);
                acc1[0] = fmaf(v1, w0.x, acc1[0]); acc1[1] = fmaf(v1, w0.y, acc1[1]);
                acc1[2] = fmaf(v1, w0.z, acc1[2]); acc1[3] = fmaf(v1, w0.w, acc1[3]);
                acc1[4] = fmaf(v1, w1.x, acc1[4]); acc1[5] = fmaf(v1, w1.y, acc1[5]);
                acc1[6] = fmaf(v1, w1.z, acc1[6]); acc1[7] = fmaf(v1, w1.w, acc1[7]);
                acc1[8] = fmaf(v1, w2.x, acc1[8]); acc1[9] = fmaf(v1, w2.y, acc1[9]);
                acc1[10] = fmaf(v1, w2.z, acc1[10]); acc1[11] = fmaf(v1, w2.w, acc1[11]);
            }
        }
    }
    float4* o0 = (float4*)(&xgl[(2 * ti) * XGS + g0]);
    float4* o1 = (float4*)(&xgl[(2 * ti + 1) * XGS + g0]);
    o0[0] = make_float4(acc0[0], acc0[1], acc0[2], acc0[3]);
    o0[1] = make_float4(acc0[4], acc0[5], acc0[6], acc0[7]);
    o0[2] = make_float4(acc0[8], acc0[9], acc0[10], acc0[11]);
    o1[0] = make_float4(acc1[0], acc1[1], acc1[2], acc1[3]);
    o1[1] = make_float4(acc1[4], acc1[5], acc1[6], acc1[7]);
    o1[2] = make_float4(acc1[8], acc1[9], acc1[10], acc1[11]);
}

// ---- GEMM phase, layer 0 (K = 5, x rows stride 5, scalar loads) ----
__device__ __forceinline__ void gemm5(
    const float* __restrict__ xb, int c, int ti, int g0,
    const float* __restrict__ Wt, float* __restrict__ xgl)
{
    const float* p0 = xb + (size_t)(c * CHUNK + 2 * ti) * 5;
    const float* p1 = p0 + 5;
    float xv0[5], xv1[5];
    #pragma unroll
    for (int k = 0; k < 5; ++k) { xv0[k] = p0[k]; xv1[k] = p1[k]; }
    float acc0[12], acc1[12];
    #pragma unroll
    for (int i = 0; i < 12; ++i) { acc0[i] = 0.f; acc1[i] = 0.f; }
    #pragma unroll
    for (int k = 0; k < 5; ++k) {
        const float4* w = (const float4*)(&Wt[k * 192 + g0]);
        float4 w0 = w[0], w1 = w[1], w2 = w[2];
        float v0 = xv0[k], v1 = xv1[k];
        acc0[0] = fmaf(v0, w0.x, acc0[0]); acc0[1] = fmaf(v0, w0.y, acc0[1]);
        acc0[2] = fmaf(v0, w0.z, acc0[2]); acc0[3] = fmaf(v0, w0.w, acc0[3]);
        acc0[4] = fmaf(v0, w1.x, acc0[4]); acc0[5] = fmaf(v0, w1.y, acc0[5]);
        acc0[6] = fmaf(v0, w1.z, acc0[6]); acc0[7] = fmaf(v0, w1.w, acc0[7]);
        acc0[8] = fmaf(v0, w2.x, acc0[8]); acc0[9] = fmaf(v0, w2.y, acc0[9]);
        acc0[10] = fmaf(v0, w2.z, acc0[10]); acc0[11] = fmaf(v0, w2.w, acc0[11]);
        acc1[0] = fmaf(v1, w0.x, acc1[0]); acc1[1] = fmaf(v1, w0.y, acc1[1]);
        acc1[2] = fmaf(v1, w0.z, acc1[2]); acc1[3] = fmaf(v1, w0.w, acc1[3]);
        acc1[4] = fmaf(v1, w1.x, acc1[4]); acc1[5] = fmaf(v1, w1.y, acc1[5]);
        acc1[6] = fmaf(v1, w1.z, acc1[6]); acc1[7] = fmaf(v1, w1.w, acc1[7]);
        acc1[8] = fmaf(v1, w2.x, acc1[8]); acc1[9] = fmaf(v1, w2.y, acc1[9]);
        acc1[10] = fmaf(v1, w2.z, acc1[10]); acc1[11] = fmaf(v1, w2.w, acc1[11]);
    }
    float4* o0 = (float4*)(&xgl[(2 * ti) * XGS + g0]);
    float4* o1 = (float4*)(&xgl[(2 * ti + 1) * XGS + g0]);
    o0[0] = make_float4(acc0[0], acc0[1], acc0[2], acc0[3]);
    o0[1] = make_float4(acc0[4], acc0[5], acc0[6], acc0[7]);
    o0[2] = make_float4(acc0[8], acc0[9], acc0[10], acc0[11]);
    o1[0] = make_float4(acc1[0], acc1[1], acc1[2], acc1[3]);
    o1[1] = make_float4(acc1[4], acc1[5], acc1[6], acc1[7]);
    o1[2] = make_float4(acc1[8], acc1[9], acc1[10], acc1[11]);
}

__global__ __launch_bounds__(NTHR, 2) void gru_all_kernel(
    const float* __restrict__ x,
    const float* __restrict__ w_ih0, const float* __restrict__ w_hh0,
    const float* __restrict__ b_ih0, const float* __restrict__ b_hh0,
    const float* __restrict__ w_ih, const float* __restrict__ w_hh,
    const float* __restrict__ b_ih, const float* __restrict__ b_hh,
    const float* __restrict__ w_fc, const float* __restrict__ b_fc,
    float* __restrict__ out, float* __restrict__ act)
{
    __shared__ float Wt[64 * 192];              // 48 KiB, k-major x-side weights
    __shared__ __align__(16) float xgl[CHUNK * XGS];  // 24.5 KiB
    __shared__ __align__(16) float hbuf[2][H];
    __shared__ float partial[4];

    const int tid  = threadIdx.x;
    const int wv   = tid >> 6;
    const int lane = tid & 63;
    const int b    = blockIdx.x;
    // recurrence mapping (round 8): j = 16wv+jl, ks 4-way
    const int jl = lane & 15;
    const int ks = lane >> 4;
    const int j  = wv * 16 + jl;
    const int k0 = ks * 16;
    const int bpaddr = (lane ^ 32) << 2;
    // GEMM mapping: 2t x 12g tile
    const int ti = tid >> 4;          // 0..15 -> t rows {2ti, 2ti+1}
    const int g0 = (tid & 15) * 12;   // 0..180

    float* __restrict__ actb = act + (size_t)b * (SEQ_T * H);
    const float* __restrict__ xb = x + (size_t)b * (SEQ_T * 5);

    float hlast = 0.0f;

    for (int layer = 0; layer < 5; ++layer) {
        const bool l0 = (layer == 0);
        const bool dostore = (layer < 4);

        // Full drain: prev layer's act stores visible before this layer's
        // GEMM reads them; all LDS reads of old Wt/xg finished.
        __syncthreads();

        // ---- stage W_ih (k-major) into LDS, once per layer ----
        if (l0) {
            for (int idx = tid; idx < 192 * 5; idx += NTHR) {
                int g = idx / 5, k = idx - g * 5;
                Wt[k * 192 + g] = w_ih0[idx];
            }
        } else {
            const float* wip = w_ih + (size_t)(layer - 1) * (192 * H);
            for (int idx = tid; idx < 192 * 64; idx += NTHR)
                Wt[(idx & 63) * 192 + (idx >> 6)] = wip[idx];
        }

        // ---- h-side weights + biases -> regs (round-8 mapping) ----
        float4 wHv[3][4];
        {
            const float* whp = l0 ? w_hh0 : w_hh + (size_t)(layer - 1) * (192 * H);
            #pragma unroll
            for (int g = 0; g < 3; ++g) {
                const float4* row = (const float4*)(whp + (g * 64 + j) * H + k0);
                #pragma unroll
                for (int q = 0; q < 4; ++q) wHv[g][q] = row[q];
            }
        }
        float bR, bZ, bNi, bNh;
        {
            const float* bip = l0 ? b_ih0 : b_ih + (layer - 1) * 192;
            const float* bhp = l0 ? b_hh0 : b_hh + (layer - 1) * 192;
            bR  = bip[j] + bhp[j];
            bZ  = bip[j + 64] + bhp[j + 64];
            bNi = bip[j + 128];
            bNh = bhp[j + 128];
        }

        if (ks == 0) hbuf[0][j] = 0.0f;   // h0 = 0
        __syncthreads();                  // Wt + hbuf visible

        float hprev = 0.0f;
        float* pSt = actb + j;

        for (int c = 0; c < NCHUNK; ++c) {
            // ---- GEMM phase: all waves fill xg for this chunk ----
            if (l0) gemm5(xb, c, ti, g0, Wt, xgl);
            else    gemm64(actb, c, ti, g0, Wt, xgl);
            LDS_BARRIER();   // xg visible

            // ---- REC phase: 32 lean steps (no global-load-use inside) ----
            const float* xgp = xgl;
            #pragma unroll 4
            for (int tt = 0; tt < CHUNK; tt += 2) {
                rec_step<0>(xgp, hbuf, wHv, bR, bZ, bNi, bNh,
                            hprev, j, k0, ks, bpaddr, pSt, dostore);
                xgp += XGS;
                LDS_BARRIER();
                rec_step<1>(xgp, hbuf, wHv, bR, bZ, bNi, bNh,
                            hprev, j, k0, ks, bpaddr, pSt, dostore);
                xgp += XGS;
                LDS_BARRIER();   // also guards xg overwrite next chunk
            }
        }

        if (layer == 4) hlast = hprev;
    }

    // ---- fused FC on last timestep: out[b] = h . w_fc + b_fc ----
    float v = (ks == 0) ? hlast * w_fc[j] : 0.0f;
    v += __shfl_xor(v, 1, 64);
    v += __shfl_xor(v, 2, 64);
    v += __shfl_xor(v, 4, 64);
    v += __shfl_xor(v, 8, 64);
    if (lane == 0) partial[wv] = v;
    __syncthreads();
    if (tid == 0) out[b] = partial[0] + partial[1] + partial[2] + partial[3] + b_fc[0];
}

extern "C" void kernel_launch(void* const* d_in, const int* in_sizes, int n_in,
                              void* d_out, int out_size, void* d_ws, size_t ws_size,
                              hipStream_t stream) {
    const float* x     = (const float*)d_in[0];
    const float* w_ih0 = (const float*)d_in[1];
    const float* w_hh0 = (const float*)d_in[2];
    const float* b_ih0 = (const float*)d_in[3];
    const float* b_hh0 = (const float*)d_in[4];
    const float* w_ih  = (const float*)d_in[5];
    const float* w_hh  = (const float*)d_in[6];
    const float* b_ih  = (const float*)d_in[7];
    const float* b_hh  = (const float*)d_in[8];
    const float* w_fc  = (const float*)d_in[9];
    const float* b_fc  = (const float*)d_in[10];
    float* out = (float*)d_out;
    float* act = (float*)d_ws;  // [BATCH][SEQ_T][H] fp32 = 128 MiB

    hipLaunchKernelGGL(gru_all_kernel, dim3(NBLK), dim3(NTHR), 0, stream,
                       x, w_ih0, w_hh0, b_ih0, b_hh0,
                       w_ih, w_hh, b_ih, b_hh, w_fc, b_fc, out, act);
}